// Round 1
// baseline (975.310 us; speedup 1.0000x reference)
//
#include <hip/hip_runtime.h>
#include <hip/hip_bf16.h>

// Problem constants (from reference): B=4, C_IN=C_OUT=64, N=100000, K=6
#define BB   4
#define NN   100000
#define CC   64
#define KK   6
#define EPSV 1e-5f

using bf16 = __hip_bfloat16;

__device__ __forceinline__ float b2f(bf16 v)  { return __bfloat162float(v); }
__device__ __forceinline__ bf16  f2b(float v) { return __float2bfloat16(v); }

// ---------------------------------------------------------------------------
// K_prep: transpose weights [O][C][2] (=[O][128]) -> [128][O] so that lane o
// can load its whole weight column coalesced (lane-consecutive addresses).
// ---------------------------------------------------------------------------
__global__ void wprep_k(const float* __restrict__ W0, const float* __restrict__ W1,
                        float* __restrict__ W0t, float* __restrict__ W1t)
{
    int t = blockIdx.x * 256 + threadIdx.x;
    if (t < 64 * 128) {
        int o = t >> 7, j = t & 127;
        W0t[j * 64 + o] = W0[t];
        W1t[j * 64 + o] = W1[t];
    }
}

// ---------------------------------------------------------------------------
// K0: transpose x [B,C,N] fp32 -> xT [B,N,C] bf16 (so gathers read one
// contiguous 128B row per neighbor instead of 64 strided cache lines).
// ---------------------------------------------------------------------------
__global__ __launch_bounds__(256) void xpose_k(const float* __restrict__ x,
                                               bf16* __restrict__ xT)
{
    __shared__ float tile[64][65];            // +1 pad: conflict-free both phases
    const int b  = blockIdx.y;
    const int n0 = blockIdx.x * 64;
    const int tx = threadIdx.x & 63;
    const int ty = threadIdx.x >> 6;
    const float* xb = x + (size_t)b * 64 * NN;
    const int n = n0 + tx;
#pragma unroll
    for (int cc = 0; cc < 64; cc += 4) {      // each wave handles one c-row/iter
        const int c = cc + ty;
        tile[tx][c] = (n < NN) ? xb[(size_t)c * NN + n] : 0.f;
    }
    __syncthreads();
#pragma unroll
    for (int rr = 0; rr < 64; rr += 4) {
        const int nl = rr + ty;
        const int n2 = n0 + nl;
        if (n2 < NN) xT[((size_t)b * NN + n2) * 64 + tx] = f2b(tile[nl][tx]);
    }
}

// ---------------------------------------------------------------------------
// K1: conv1. Per wave: 32 points. Lane c builds G[2c]=center, G[2c+1]=nb-sum
// in LDS; lane o holds W0 column (128 VGPRs) and accumulates h[o] via LDS
// broadcast reads. Also accumulates relu-stats (sum, sumsq) per channel.
// Writes hT [B,N,O] bf16 (coalesced 128B rows) — doubles as residual source.
// ---------------------------------------------------------------------------
__global__ __launch_bounds__(256, 2) void conv1_k(
    const bf16* __restrict__ xT, const int* __restrict__ neigh,
    const float* __restrict__ W0t, bf16* __restrict__ hT,
    float* __restrict__ stats)
{
    __shared__ float G[4][128];
    __shared__ float red[4][128];
    const int b    = blockIdx.y;
    const int wave = threadIdx.x >> 6;
    const int lane = threadIdx.x & 63;

    float w[128];                              // per-lane weight column in VGPRs
#pragma unroll
    for (int j = 0; j < 128; ++j) w[j] = W0t[j * 64 + lane];

    const bf16* xTb = xT + (size_t)b * NN * 64;
    const int*  nbb = neigh + (size_t)b * NN * 6;
    float s1 = 0.f, s2 = 0.f;
    const int n0 = blockIdx.x * 128 + wave * 32;

    for (int i = 0; i < 32; ++i) {
        const int n   = n0 + i;
        const bool act = (n < NN);
        const int nc  = act ? n : (NN - 1);

        float cen = b2f(xTb[nc * 64 + lane]);
        const int* nb = nbb + nc * 6;
        float s = 0.f;
#pragma unroll
        for (int k = 0; k < KK; ++k)
            s += b2f(xTb[nb[k] * 64 + lane]);

        G[wave][2 * lane]     = cen;
        G[wave][2 * lane + 1] = s;
        __syncthreads();

        float a0 = 0.f, a1 = 0.f, a2 = 0.f, a3 = 0.f;
        const float4* g4 = (const float4*)(&G[wave][0]);
#pragma unroll
        for (int j = 0; j < 32; ++j) {
            float4 g = g4[j];
            a0 = fmaf(g.x, w[4 * j + 0], a0);
            a1 = fmaf(g.y, w[4 * j + 1], a1);
            a2 = fmaf(g.z, w[4 * j + 2], a2);
            a3 = fmaf(g.w, w[4 * j + 3], a3);
        }
        __syncthreads();                       // G consumed before next overwrite

        float h = (a0 + a1) + (a2 + a3);
        if (act) {
            hT[((size_t)b * NN + n) * 64 + lane] = f2b(h);
            float r = fmaxf(h, 0.f);
            s1 += r;
            s2 = fmaf(r, r, s2);
        }
    }

    red[wave][lane]      = s1;
    red[wave][64 + lane] = s2;
    __syncthreads();
    if (threadIdx.x < 128) {
        float v = red[0][threadIdx.x] + red[1][threadIdx.x]
                + red[2][threadIdx.x] + red[3][threadIdx.x];
        atomicAdd(&stats[threadIdx.x], v);     // device-scope, 128 addrs/block
    }
}

// ---------------------------------------------------------------------------
// K2: fold BN stats into per-channel affine: rhat = a*relu(h) + bconst.
// ---------------------------------------------------------------------------
__global__ void bnab_k(const float* __restrict__ stats,
                       const float* __restrict__ gamma,
                       const float* __restrict__ beta,
                       float* __restrict__ ab)
{
    const int o = threadIdx.x;
    if (o < 64) {
        const float inv = 1.f / (float)(BB * NN);
        float mean = stats[o] * inv;
        float var  = stats[64 + o] * inv - mean * mean;   // biased var (jnp.var)
        float a    = gamma[o] * rsqrtf(var + EPSV);
        ab[o]      = a;
        ab[64 + o] = fmaf(-a, mean, beta[o]);
    }
}

// ---------------------------------------------------------------------------
// K3: conv2 + residual + relu. BN applied on the fly during G build
// (affine per channel commutes with neighbor-sum: sum rhat = a*sum r + 6b).
// Output staged in LDS tile and written transposed/coalesced to [B,O,N].
// ---------------------------------------------------------------------------
__global__ __launch_bounds__(256, 2) void conv2_k(
    const bf16* __restrict__ hT, const int* __restrict__ neigh,
    const float* __restrict__ W1t, const float* __restrict__ ab,
    float* __restrict__ out)
{
    __shared__ float G[4][128];
    __shared__ float tile[128][65];            // +1 pad: conflict-free transpose
    const int b    = blockIdx.y;
    const int wave = threadIdx.x >> 6;
    const int lane = threadIdx.x & 63;

    float w[128];
#pragma unroll
    for (int j = 0; j < 128; ++j) w[j] = W1t[j * 64 + lane];

    const float ac = ab[lane];
    const float bc = ab[64 + lane];
    const float b6 = 6.f * bc;

    const bf16* hTb = hT + (size_t)b * NN * 64;
    const int*  nbb = neigh + (size_t)b * NN * 6;
    const int n0 = blockIdx.x * 128;

    for (int i = 0; i < 32; ++i) {
        const int p = wave * 32 + i;
        const int n = n0 + p;
        const bool act = (n < NN);
        const int nc = act ? n : (NN - 1);

        float hc = b2f(hTb[nc * 64 + lane]);   // pre-relu center = residual x1
        const int* nb = nbb + nc * 6;
        float rs = 0.f;
#pragma unroll
        for (int k = 0; k < KK; ++k)
            rs += fmaxf(b2f(hTb[nb[k] * 64 + lane]), 0.f);

        G[wave][2 * lane]     = fmaf(ac, fmaxf(hc, 0.f), bc);
        G[wave][2 * lane + 1] = fmaf(ac, rs, b6);
        __syncthreads();

        float a0 = 0.f, a1 = 0.f, a2 = 0.f, a3 = 0.f;
        const float4* g4 = (const float4*)(&G[wave][0]);
#pragma unroll
        for (int j = 0; j < 32; ++j) {
            float4 g = g4[j];
            a0 = fmaf(g.x, w[4 * j + 0], a0);
            a1 = fmaf(g.y, w[4 * j + 1], a1);
            a2 = fmaf(g.z, w[4 * j + 2], a2);
            a3 = fmaf(g.w, w[4 * j + 3], a3);
        }
        __syncthreads();

        float h2 = (a0 + a1) + (a2 + a3) + hc; // + residual
        tile[p][lane] = fmaxf(h2, 0.f);
    }
    __syncthreads();

    // transposed, coalesced store: wave w writes o in [16w, 16w+16)
#pragma unroll
    for (int r = 0; r < 16; ++r) {
        const int o = wave * 16 + r;
#pragma unroll
        for (int jj = 0; jj < 2; ++jj) {
            const int nn2 = jj * 64 + lane;
            const int n   = n0 + nn2;
            if (n < NN) out[((size_t)b * 64 + o) * NN + n] = tile[nn2][o];
        }
    }
}

// ---------------------------------------------------------------------------
// Workspace layout (bytes):
//   xT   [B,N,64] bf16 :      0 .. 51,200,000
//   hT   [B,N,64] bf16 : 51.2M .. 102,400,000
//   stats[128]    f32  : 102,400,000
//   ab   [128]    f32  : 102,400,512
//   W0t  [128,64] f32  : 102,401,024
//   W1t  [128,64] f32  : 102,433,792     (total ~97.7 MiB)
// ---------------------------------------------------------------------------
extern "C" void kernel_launch(void* const* d_in, const int* in_sizes, int n_in,
                              void* d_out, int out_size, void* d_ws, size_t ws_size,
                              hipStream_t stream)
{
    const float* x     = (const float*)d_in[0];
    const int*   neigh = (const int*)d_in[1];
    const float* W0    = (const float*)d_in[2];
    const float* W1    = (const float*)d_in[3];
    const float* gamma = (const float*)d_in[4];
    const float* beta  = (const float*)d_in[5];
    float* out = (float*)d_out;

    char* ws = (char*)d_ws;
    bf16*  xT    = (bf16*)(ws + 0);
    bf16*  hT    = (bf16*)(ws + 51200000);
    float* stats = (float*)(ws + 102400000);
    float* ab    = (float*)(ws + 102400512);
    float* W0t   = (float*)(ws + 102401024);
    float* W1t   = (float*)(ws + 102433792);

    hipMemsetAsync(stats, 0, 512, stream);
    wprep_k<<<dim3(32), dim3(256), 0, stream>>>(W0, W1, W0t, W1t);
    xpose_k<<<dim3((NN + 63) / 64, BB), dim3(256), 0, stream>>>(x, xT);
    conv1_k<<<dim3((NN + 127) / 128, BB), dim3(256), 0, stream>>>(xT, neigh, W0t, hT, stats);
    bnab_k<<<dim3(1), dim3(64), 0, stream>>>(stats, gamma, beta, ab);
    conv2_k<<<dim3((NN + 127) / 128, BB), dim3(256), 0, stream>>>(hT, neigh, W1t, ab, out);
}

// Round 2
// 883.057 us; speedup vs baseline: 1.1045x; 1.1045x over previous
//
#include <hip/hip_runtime.h>
#include <hip/hip_bf16.h>

// Problem constants: B=4, C_IN=C_OUT=64, N=100000, K=6
#define BB   4
#define NN   100000
#define KK   6
#define EPSV 1e-5f

using bf16 = __hip_bfloat16;
typedef __attribute__((ext_vector_type(8))) short  short8;   // 8 bf16 = 4 VGPRs
typedef __attribute__((ext_vector_type(4))) float  float4v;  // MFMA C/D

__device__ __forceinline__ float u2f(unsigned u) {          // raw bf16 -> f32
    union { unsigned x; float f; } c; c.x = u << 16; return c.f;
}
__device__ __forceinline__ unsigned f2bu(float f) {         // f32 -> raw bf16 (RNE)
    union { bf16 h; unsigned short u; } c; c.h = __float2bfloat16(f); return c.u;
}

// ---------------------------------------------------------------------------
// wprep: swizzle W[o][128] (j = 2c+s2 matches our G packing) into MFMA
// B-fragment order: Wf[((s*4+t)*64 + lane)*8 + i] = bf16(W[o=16t+(lane&15)]
//                                                        [j=32s+8*(lane>>4)+i])
// so conv kernels load each fragment with one lane-consecutive b128.
// ---------------------------------------------------------------------------
__global__ void wprep_k(const float* __restrict__ W0, const float* __restrict__ W1,
                        unsigned short* __restrict__ Wf0, unsigned short* __restrict__ Wf1)
{
    int tid = blockIdx.x * 256 + threadIdx.x;   // 8192 total
    if (tid < 8192) {
        int i = tid & 7, lane = (tid >> 3) & 63, t = (tid >> 9) & 3, s = tid >> 11;
        int o = t * 16 + (lane & 15);
        int j = s * 32 + (lane >> 4) * 8 + i;
        Wf0[tid] = f2bu(W0[o * 128 + j]);
        Wf1[tid] = f2bu(W1[o * 128 + j]);
    }
}

// ---------------------------------------------------------------------------
// xpose: x [B,C,N] f32 -> xT [B,N,C] bf16 (contiguous 128B row per gather).
// ---------------------------------------------------------------------------
__global__ __launch_bounds__(256) void xpose_k(const float* __restrict__ x,
                                               bf16* __restrict__ xT)
{
    __shared__ float tile[64][65];
    const int b  = blockIdx.y;
    const int n0 = blockIdx.x * 64;
    const int tx = threadIdx.x & 63;
    const int ty = threadIdx.x >> 6;
    const float* xb = x + (size_t)b * 64 * NN;
    const int n = n0 + tx;
#pragma unroll
    for (int cc = 0; cc < 64; cc += 4) {
        const int c = cc + ty;
        tile[tx][c] = (n < NN) ? xb[(size_t)c * NN + n] : 0.f;
    }
    __syncthreads();
#pragma unroll
    for (int rr = 0; rr < 64; rr += 4) {
        const int nl = rr + ty;
        const int n2 = n0 + nl;
        if (n2 < NN) xT[((size_t)b * NN + n2) * 64 + tx] = __float2bfloat16(tile[nl][tx]);
    }
}

// ---------------------------------------------------------------------------
// conv1 (MFMA): per wave, 4 chunks of 32 points.
//  Phase A: gather (center + 6-neighbor sum) per channel lane -> packed bf16
//           pair at Gs word [m*68 + c]  (stride 68: writes 2-way free, b128
//           A-frag reads perfectly bank-balanced).
//  Phase B: 32x MFMA 16x16x32 bf16 (2 point-halves x 4 n-tiles x 4 k-steps).
//  Epilogue: write hT [B,N,64] bf16 (pre-relu, = residual source) + BN stats.
// ---------------------------------------------------------------------------
__global__ __launch_bounds__(256, 2) void conv1_k(
    const bf16* __restrict__ xT, const int* __restrict__ neigh,
    const unsigned short* __restrict__ Wf0, bf16* __restrict__ hT,
    float* __restrict__ stats)
{
    __shared__ __align__(16) unsigned Gs[4][32 * 68];
    __shared__ float redA[4][4][64];
    __shared__ float redB[4][4][64];

    const int b    = blockIdx.y;
    const int wave = threadIdx.x >> 6;
    const int lane = threadIdx.x & 63;
    const int col  = lane & 15;
    const int quad = lane >> 4;

    short8 bw[4][4];                         // B fragments: 64 VGPRs, loaded once
#pragma unroll
    for (int s = 0; s < 4; ++s)
#pragma unroll
        for (int t = 0; t < 4; ++t)
            bw[s][t] = *(const short8*)(Wf0 + ((s * 4 + t) * 64 + lane) * 8);

    const unsigned short* xb = (const unsigned short*)xT + (size_t)b * NN * 64;
    const int* nbb = neigh + (size_t)b * NN * 6;
    unsigned* G = Gs[wave];
    float sA[4] = {0, 0, 0, 0}, sB[4] = {0, 0, 0, 0};

    for (int ck = 0; ck < 4; ++ck) {
        const int cn0 = blockIdx.x * 512 + wave * 128 + ck * 32;
        __syncthreads();
        // ---- Phase A: gather, no intra-phase barriers (loads pipeline) ----
#pragma unroll 4
        for (int m = 0; m < 32; ++m) {
            const int n  = cn0 + m;
            const int nc = (n < NN) ? n : (NN - 1);
            unsigned cen = xb[(size_t)nc * 64 + lane];
            const int* nb = nbb + (size_t)nc * 6;
            float s = 0.f;
#pragma unroll
            for (int k = 0; k < KK; ++k)
                s += u2f(xb[(size_t)nb[k] * 64 + lane]);
            G[m * 68 + lane] = cen | (f2bu(s) << 16);   // (j=2c, j=2c+1)
        }
        __syncthreads();

        // ---- Phase B: MFMA ----
        float4v acc[2][4];
#pragma unroll
        for (int h = 0; h < 2; ++h)
#pragma unroll
            for (int t = 0; t < 4; ++t) acc[h][t] = (float4v){0.f, 0.f, 0.f, 0.f};
#pragma unroll
        for (int h = 0; h < 2; ++h) {
            short8 af[4];
#pragma unroll
            for (int s = 0; s < 4; ++s)  // A[m=lane&15][k=quad*8+i], 16B aligned
                af[s] = *(const short8*)&G[(h * 16 + col) * 68 + s * 16 + quad * 4];
#pragma unroll
            for (int s = 0; s < 4; ++s)
#pragma unroll
                for (int t = 0; t < 4; ++t)
                    acc[h][t] = __builtin_amdgcn_mfma_f32_16x16x32_bf16(
                        af[s], bw[s][t], acc[h][t], 0, 0, 0);
        }

        // ---- Epilogue: D[m=quad*4+reg][o=16t+col]; store hT + BN stats ----
#pragma unroll
        for (int h = 0; h < 2; ++h)
#pragma unroll
            for (int t = 0; t < 4; ++t)
#pragma unroll
                for (int r = 0; r < 4; ++r) {
                    const int n = cn0 + h * 16 + quad * 4 + r;
                    if (n < NN) {
                        float v = acc[h][t][r];
                        hT[((size_t)b * NN + n) * 64 + t * 16 + col] = __float2bfloat16(v);
                        float rv = fmaxf(v, 0.f);
                        sA[t] += rv;
                        sB[t]  = fmaf(rv, rv, sB[t]);
                    }
                }
    }

    // ---- block-level BN stats reduction, one atomicAdd per channel ----
#pragma unroll
    for (int t = 0; t < 4; ++t) {
        redA[wave][quad][t * 16 + col] = sA[t];
        redB[wave][quad][t * 16 + col] = sB[t];
    }
    __syncthreads();
    if (threadIdx.x < 128) {
        const int sel = threadIdx.x >> 6, o = threadIdx.x & 63;
        float v = 0.f;
#pragma unroll
        for (int w = 0; w < 4; ++w)
#pragma unroll
            for (int q = 0; q < 4; ++q)
                v += sel ? redB[w][q][o] : redA[w][q][o];
        atomicAdd(&stats[sel * 64 + o], v);
    }
}

// ---------------------------------------------------------------------------
// bnab: fold train-mode BN into per-channel affine rhat = a*relu(h) + b.
// ---------------------------------------------------------------------------
__global__ void bnab_k(const float* __restrict__ stats,
                       const float* __restrict__ gamma,
                       const float* __restrict__ beta,
                       float* __restrict__ ab)
{
    const int o = threadIdx.x;
    if (o < 64) {
        const float inv = 1.f / (float)(BB * NN);
        float mean = stats[o] * inv;
        float var  = stats[64 + o] * inv - mean * mean;   // biased var (jnp.var)
        float a    = gamma[o] * rsqrtf(var + EPSV);
        ab[o]      = a;
        ab[64 + o] = fmaf(-a, mean, beta[o]);
    }
}

// ---------------------------------------------------------------------------
// conv2 (MFMA): gather applies BN affine on the fly (commutes with nb-sum:
// sum rhat = a*sum relu + 6b). Epilogue adds residual (hT re-read, L1-hot),
// relu, LDS-transposes and writes out [B,O,N] f32 with 128B-coalesced stores.
// ---------------------------------------------------------------------------
__global__ __launch_bounds__(256, 2) void conv2_k(
    const bf16* __restrict__ hT, const int* __restrict__ neigh,
    const unsigned short* __restrict__ Wf1, const float* __restrict__ ab,
    float* __restrict__ out)
{
    __shared__ __align__(16) unsigned Gs[4][32 * 68];
    __shared__ float tile[4][64 * 33];

    const int b    = blockIdx.y;
    const int wave = threadIdx.x >> 6;
    const int lane = threadIdx.x & 63;
    const int col  = lane & 15;
    const int quad = lane >> 4;

    short8 bw[4][4];
#pragma unroll
    for (int s = 0; s < 4; ++s)
#pragma unroll
        for (int t = 0; t < 4; ++t)
            bw[s][t] = *(const short8*)(Wf1 + ((s * 4 + t) * 64 + lane) * 8);

    const float acl = ab[lane];
    const float bcl = ab[64 + lane];
    const float b6  = 6.f * bcl;

    const unsigned short* hb = (const unsigned short*)hT + (size_t)b * NN * 64;
    const int* nbb = neigh + (size_t)b * NN * 6;
    unsigned* G = Gs[wave];
    float* tl   = tile[wave];

    for (int ck = 0; ck < 4; ++ck) {
        const int cn0 = blockIdx.x * 512 + wave * 128 + ck * 32;
        __syncthreads();
        // ---- gather + fused BN affine ----
#pragma unroll 4
        for (int m = 0; m < 32; ++m) {
            const int n  = cn0 + m;
            const int nc = (n < NN) ? n : (NN - 1);
            float hc = u2f(hb[(size_t)nc * 64 + lane]);
            const int* nb = nbb + (size_t)nc * 6;
            float rs = 0.f;
#pragma unroll
            for (int k = 0; k < KK; ++k)
                rs += fmaxf(u2f(hb[(size_t)nb[k] * 64 + lane]), 0.f);
            unsigned lo = f2bu(fmaf(acl, fmaxf(hc, 0.f), bcl));
            unsigned hi = f2bu(fmaf(acl, rs, b6));
            G[m * 68 + lane] = lo | (hi << 16);
        }
        __syncthreads();

        // ---- MFMA ----
        float4v acc[2][4];
#pragma unroll
        for (int h = 0; h < 2; ++h)
#pragma unroll
            for (int t = 0; t < 4; ++t) acc[h][t] = (float4v){0.f, 0.f, 0.f, 0.f};
#pragma unroll
        for (int h = 0; h < 2; ++h) {
            short8 af[4];
#pragma unroll
            for (int s = 0; s < 4; ++s)
                af[s] = *(const short8*)&G[(h * 16 + col) * 68 + s * 16 + quad * 4];
#pragma unroll
            for (int s = 0; s < 4; ++s)
#pragma unroll
                for (int t = 0; t < 4; ++t)
                    acc[h][t] = __builtin_amdgcn_mfma_f32_16x16x32_bf16(
                        af[s], bw[s][t], acc[h][t], 0, 0, 0);
        }
        __syncthreads();

        // ---- epilogue: + residual, relu, stage transposed in LDS ----
#pragma unroll
        for (int h = 0; h < 2; ++h)
#pragma unroll
            for (int t = 0; t < 4; ++t)
#pragma unroll
                for (int r = 0; r < 4; ++r) {
                    const int ml = h * 16 + quad * 4 + r;
                    const int n  = cn0 + ml;
                    if (n < NN) {
                        float res = u2f(hb[(size_t)n * 64 + t * 16 + col]);
                        float v   = acc[h][t][r] + res;
                        tl[(t * 16 + col) * 33 + ml] = fmaxf(v, 0.f);
                    }
                }
        __syncthreads();

        // ---- coalesced store: 2 x 128B segments per instruction ----
        const int half = lane >> 5, c32 = lane & 31;
        const int n = cn0 + c32;
        if (n < NN) {
#pragma unroll
            for (int orow = 0; orow < 32; ++orow) {
                const int o = half * 32 + orow;
                out[((size_t)b * 64 + o) * NN + n] = tl[o * 33 + c32];
            }
        }
    }
}

// ---------------------------------------------------------------------------
// Workspace layout (bytes):
//   xT  [B,N,64] bf16 :           0 .. 51,200,000
//   hT  [B,N,64] bf16 :  51,200,000 .. 102,400,000
//   stats[128]   f32  : 102,400,000
//   ab   [128]   f32  : 102,400,512
//   Wf0  [8192]  bf16 : 102,401,024
//   Wf1  [8192]  bf16 : 102,417,408   (end 102,433,792)
// ---------------------------------------------------------------------------
extern "C" void kernel_launch(void* const* d_in, const int* in_sizes, int n_in,
                              void* d_out, int out_size, void* d_ws, size_t ws_size,
                              hipStream_t stream)
{
    const float* x     = (const float*)d_in[0];
    const int*   neigh = (const int*)d_in[1];
    const float* W0    = (const float*)d_in[2];
    const float* W1    = (const float*)d_in[3];
    const float* gamma = (const float*)d_in[4];
    const float* beta  = (const float*)d_in[5];
    float* out = (float*)d_out;

    char* ws = (char*)d_ws;
    bf16*           xT    = (bf16*)(ws + 0);
    bf16*           hT    = (bf16*)(ws + 51200000);
    float*          stats = (float*)(ws + 102400000);
    float*          ab    = (float*)(ws + 102400512);
    unsigned short* Wf0   = (unsigned short*)(ws + 102401024);
    unsigned short* Wf1   = (unsigned short*)(ws + 102417408);

    hipMemsetAsync(stats, 0, 512, stream);
    wprep_k<<<dim3(32), dim3(256), 0, stream>>>(W0, W1, Wf0, Wf1);
    xpose_k<<<dim3((NN + 63) / 64, BB), dim3(256), 0, stream>>>(x, xT);
    conv1_k<<<dim3((NN + 511) / 512, BB), dim3(256), 0, stream>>>(xT, neigh, Wf0, hT, stats);
    bnab_k<<<dim3(1), dim3(64), 0, stream>>>(stats, gamma, beta, ab);
    conv2_k<<<dim3((NN + 511) / 512, BB), dim3(256), 0, stream>>>(hT, neigh, Wf1, ab, out);
}